// Round 7
// baseline (2004.762 us; speedup 1.0000x reference)
//
#include <hip/hip_runtime.h>
#include <math.h>

#define N_ROWS 32768
#define DIM 256
#define KCODES 8192

#define BM 256                // rows per block
#define BN 128                // codes per K-step tile
#define NSLICE 8
#define SLICE_K 1024
#define NKT 8                 // SLICE_K/BN
#define NDT 8                 // DIM/32
#define NSTEP (NKT * NDT)     // 64
#define TAU 3e-4f

#define FAST_SQRT(x) __builtin_amdgcn_sqrtf(x)

// ws layout (float offsets)
#define WS_C2    0
#define WS_X2    8192
#define WS_BD    40960
#define WS_BI    73728
#define WS_L     106496
#define WS_FLAGL 139264
#define WS_AVGP  172032
#define WS_CNT   180224
#define WS_SCAL  188416      // 0=mse 1=sum p*logp 2=avg_entropy 3=pent 4=nsum
#define WS_FLAGN 188424

#define PF (NSLICE * N_ROWS)

typedef __bf16 bf16x8 __attribute__((ext_vector_type(8)));
typedef float  f32x4  __attribute__((ext_vector_type(4)));

__device__ __forceinline__ void gll16(const void* g, void* l) {
    __builtin_amdgcn_global_load_lds((const __attribute__((address_space(1))) void*)g,
                                     (__attribute__((address_space(3))) void*)l, 16, 0, 0);
}
__device__ __forceinline__ bf16x8 bcast(uint4 u) { return __builtin_bit_cast(bf16x8, u); }

// split f32 -> hi/lo bf16 + fused row sum-of-squares (8 elems/thread, 8 rows/block)
__global__ void split_k(const float* __restrict__ src, ushort* __restrict__ h,
                        ushort* __restrict__ l, float* __restrict__ norms) {
    int tid = threadIdx.x;
    int i = blockIdx.x * 256 + tid;
    const float4* s4 = (const float4*)src;
    float4 v0 = s4[2 * i], v1 = s4[2 * i + 1];
    float vv[8] = {v0.x, v0.y, v0.z, v0.w, v1.x, v1.y, v1.z, v1.w};
    float nrm = 0.f;
    uint hw[4], lw[4];
    #pragma unroll
    for (int p = 0; p < 4; ++p) {
        float a = vv[2*p], b = vv[2*p+1];
        nrm = fmaf(a, a, nrm); nrm = fmaf(b, b, nrm);
        uint ua = __float_as_uint(a), ub = __float_as_uint(b);
        uint ha = ua & 0xFFFF0000u, hb = ub & 0xFFFF0000u;
        float ra = a - __uint_as_float(ha);
        float rb = b - __uint_as_float(hb);
        hw[p] = hb | (ha >> 16);
        lw[p] = (__float_as_uint(rb) & 0xFFFF0000u) | (__float_as_uint(ra) >> 16);
    }
    ((uint4*)h)[i] = make_uint4(hw[0], hw[1], hw[2], hw[3]);
    ((uint4*)l)[i] = make_uint4(lw[0], lw[1], lw[2], lw[3]);
    #pragma unroll
    for (int off = 16; off >= 1; off >>= 1) nrm += __shfl_xor(nrm, off);
    if ((tid & 31) == 0) norms[blockIdx.x * 8 + (tid >> 5)] = nrm;
}

__global__ void init_ncbe_k(const float* __restrict__ cbe, float* __restrict__ outNcbe) {
    int i = blockIdx.x * 256 + threadIdx.x;
    float4 v = ((const float4*)cbe)[i];
    v.x *= 0.99f; v.y *= 0.99f; v.z *= 0.99f; v.w *= 0.99f;
    ((float4*)outNcbe)[i] = v;
}

__device__ __forceinline__ void online_merge(float& b1, int& i1, float& b2, float& l, float& T,
                                             float nb1, int ni1, float nb2, float nl, float nT) {
    float m  = fminf(b1, nb1);
    float fa = __expf(m - b1);
    float fb = __expf(m - nb1);
    float L  = fa * l + fb * nl;
    float TT = fa * (T + (m - b1) * l) + fb * (nT + (m - nb1) * nl);
    float losing = fmaxf(b1, nb1);
    float B2 = fminf(fminf(b2, nb2), losing);
    if (nb1 < b1 || (nb1 == b1 && ni1 < i1)) i1 = ni1;
    b1 = m; b2 = B2; l = L; T = TT;
}

// PASS 1: per-slice argmin (+2nd) + online softmax partials.  PASS 2: avg_probs for own slice.
template<int PASS>
__global__ __launch_bounds__(512, 4) void vq_mfma(const ushort* __restrict__ xh,
                                                  const ushort* __restrict__ xl,
                                                  const ushort* __restrict__ ch,
                                                  const ushort* __restrict__ cl,
                                                  float* __restrict__ ws,
                                                  float* __restrict__ P) {
    __shared__ __align__(16) ushort lds[3][8192];   // 48 KB: ring-3, cbh[0,4096) cbl[4096,8192)
    __shared__ __align__(16) float c2s[SLICE_K];    // 4 KB c2 slice cache
    __shared__ float sred[SLICE_K];                 // 4 KB (PASS2 avg_prob partials)

    const int tid  = threadIdx.x;
    const int lane = tid & 63, wid = tid >> 6;      // wid = row-group (8 x 32 rows)
    const int l15 = lane & 15, l4 = lane >> 4;
    const int slice = blockIdx.x & 7, chunk = blockIdx.x >> 3;
    const int rowBase = chunk * BM;

    // c2 slice -> LDS; sred init
    {
        const float* c2g = ws + WS_C2 + slice * SLICE_K;
        c2s[tid] = c2g[tid];
        c2s[tid + 512] = c2g[tid + 512];
        if (PASS == 2) { sred[tid] = 0.f; sred[tid + 512] = 0.f; }
    }

    // cb staging invariants: wave wid stages code-block cc=wid (16 codes), hi+lo
    const int rsub = lane >> 2, scol = lane & 3;
    const int stc = ((scol ^ ((rsub >> 1) & 3)) << 3);
    const ushort* cbh_src = ch + (((size_t)(slice * SLICE_K + wid * 16 + rsub)) << 8) + stc;
    const ushort* cbl_src = cl + (((size_t)(slice * SLICE_K + wid * 16 + rsub)) << 8) + stc;
    const int dst_off = wid * 512;

    // x fragment bases (2 rows per lane, in registers each step)
    const size_t xr0 = ((size_t)(rowBase + wid * 32 + l15)) << 8;
    const size_t xr1 = ((size_t)(rowBase + wid * 32 + 16 + l15)) << 8;
    const ushort* xb00 = xh + xr0 + (l4 << 3);
    const ushort* xb01 = xl + xr0 + (l4 << 3);
    const ushort* xb10 = xh + xr1 + (l4 << 3);
    const ushort* xb11 = xl + xr1 + (l4 << 3);

    const float x2v0 = ws[WS_X2 + rowBase + wid * 32 + l15];
    const float x2v1 = ws[WS_X2 + rowBase + wid * 32 + 16 + l15];
    float bdv0 = 0.f, bdv1 = 0.f, il0 = 0.f, il1 = 0.f;
    if (PASS == 2) {
        bdv0 = ws[WS_BD + rowBase + wid * 32 + l15];
        bdv1 = ws[WS_BD + rowBase + wid * 32 + 16 + l15];
        il0 = 1.0f / ws[WS_L + rowBase + wid * 32 + l15];
        il1 = 1.0f / ws[WS_L + rowBase + wid * 32 + 16 + l15];
    }

    float rb1[2], rb2[2], rlv[2], rTv[2]; int ri1[2];
    #pragma unroll
    for (int n = 0; n < 2; ++n) { rb1[n] = 1e30f; rb2[n] = 1e30f; rlv[n] = 0.f; rTv[n] = 0.f; ri1[n] = 0; }

    // prologue: stage t=0 -> buf0, t=1 -> buf1
    gll16(cbh_src,      &lds[0][0] + dst_off);
    gll16(cbl_src,      &lds[0][0] + 4096 + dst_off);
    gll16(cbh_src + 32, &lds[1][0] + dst_off);
    gll16(cbl_src + 32, &lds[1][0] + 4096 + dst_off);
    asm volatile("s_waitcnt vmcnt(2) lgkmcnt(0)" ::: "memory");
    __builtin_amdgcn_s_barrier();

    int rd = 0, wr = 2;
    const int abase = l15 * 32 + ((l4 ^ ((l15 >> 1) & 3)) << 3);

    for (int kt = 0; kt < NKT; ++kt) {
        f32x4 acc[8][2];
        #pragma unroll
        for (int m = 0; m < 8; ++m) {
            acc[m][0] = (f32x4){0.f, 0.f, 0.f, 0.f};
            acc[m][1] = (f32x4){0.f, 0.f, 0.f, 0.f};
        }

        #pragma unroll
        for (int dt = 0; dt < NDT; ++dt) {
            const int t = kt * 8 + dt;
            // x frags for this step (issued first: their wait also drains stage(t+1))
            uint4 u00 = *(const uint4*)(xb00 + (dt << 5));
            uint4 u01 = *(const uint4*)(xb01 + (dt << 5));
            uint4 u10 = *(const uint4*)(xb10 + (dt << 5));
            uint4 u11 = *(const uint4*)(xb11 + (dt << 5));
            if (t + 2 < NSTEP) {
                const int t2 = t + 2;
                const int off2 = ((t2 >> 3) << 15) | ((t2 & 7) << 5);
                ushort* wb = &lds[0][0] + wr * 8192;
                gll16(cbh_src + off2, wb + dst_off);
                gll16(cbl_src + off2, wb + 4096 + dst_off);
            }
            const ushort* bb = &lds[0][0] + rd * 8192;
            bf16x8 B0h = bcast(u00), B0l = bcast(u01), B1h = bcast(u10), B1l = bcast(u11);
            __builtin_amdgcn_s_setprio(1);
            #pragma unroll
            for (int m = 0; m < 8; ++m) {
                bf16x8 ah = bcast(*(const uint4*)(bb + abase + m * 512));
                bf16x8 al = bcast(*(const uint4*)(bb + 4096 + abase + m * 512));
                acc[m][0] = __builtin_amdgcn_mfma_f32_16x16x32_bf16(ah, B0h, acc[m][0], 0, 0, 0);
                acc[m][0] = __builtin_amdgcn_mfma_f32_16x16x32_bf16(ah, B0l, acc[m][0], 0, 0, 0);
                acc[m][0] = __builtin_amdgcn_mfma_f32_16x16x32_bf16(al, B0h, acc[m][0], 0, 0, 0);
                acc[m][1] = __builtin_amdgcn_mfma_f32_16x16x32_bf16(ah, B1h, acc[m][1], 0, 0, 0);
                acc[m][1] = __builtin_amdgcn_mfma_f32_16x16x32_bf16(ah, B1l, acc[m][1], 0, 0, 0);
                acc[m][1] = __builtin_amdgcn_mfma_f32_16x16x32_bf16(al, B1h, acc[m][1], 0, 0, 0);
            }
            __builtin_amdgcn_s_setprio(0);
            asm volatile("s_waitcnt vmcnt(2)" ::: "memory");
            __builtin_amdgcn_s_barrier();
            rd = (rd == 2) ? 0 : rd + 1;
            wr = (wr == 2) ? 0 : wr + 1;
        }

        // epilogue (barrier-free): lane holds D[code=m*16+l4*4+r][row n*16+l15]
        const int cb0 = slice * SLICE_K + kt * BN;
        if (PASS == 1) {
            #pragma unroll
            for (int n = 0; n < 2; ++n) {
                const float x2 = n ? x2v1 : x2v0;
                #pragma unroll
                for (int m = 0; m < 8; ++m) {
                    float4 c2v = *(const float4*)&c2s[kt * BN + m * 16 + l4 * 4];
                    float dsv[4];
                    float b1 = 1e30f, b2 = 1e30f; int i1 = 0;
                    #pragma unroll
                    for (int r = 0; r < 4; ++r) {
                        float d2 = fmaf(-2.f, acc[m][n][r], x2 + ((const float*)&c2v)[r]);
                        float dv = FAST_SQRT(fmaxf(d2, 0.f));
                        dsv[r] = dv;
                        bool better = dv < b1;
                        b2 = better ? b1 : fminf(b2, dv);
                        if (better) { b1 = dv; i1 = cb0 + m * 16 + l4 * 4 + r; }
                    }
                    float ls = 0.f, ts = 0.f;
                    #pragma unroll
                    for (int r = 0; r < 4; ++r) {
                        float e = __expf(b1 - dsv[r]);
                        ls += e;
                        ts = fmaf(e, b1 - dsv[r], ts);
                    }
                    online_merge(rb1[n], ri1[n], rb2[n], rlv[n], rTv[n], b1, i1, b2, ls, ts);
                }
            }
        } else {
            float ps[8][4];
            #pragma unroll
            for (int m = 0; m < 8; ++m)
                #pragma unroll
                for (int r = 0; r < 4; ++r) ps[m][r] = 0.f;
            #pragma unroll
            for (int n = 0; n < 2; ++n) {
                const float x2 = n ? x2v1 : x2v0;
                const float bd = n ? bdv1 : bdv0;
                const float il = n ? il1 : il0;
                #pragma unroll
                for (int m = 0; m < 8; ++m) {
                    float4 c2v = *(const float4*)&c2s[kt * BN + m * 16 + l4 * 4];
                    #pragma unroll
                    for (int r = 0; r < 4; ++r) {
                        float d2 = fmaf(-2.f, acc[m][n][r], x2 + ((const float*)&c2v)[r]);
                        float dv = FAST_SQRT(fmaxf(d2, 0.f));
                        ps[m][r] = fmaf(__expf(bd - dv), il, ps[m][r]);
                    }
                }
            }
            #pragma unroll
            for (int m = 0; m < 8; ++m)
                #pragma unroll
                for (int r = 0; r < 4; ++r) {
                    float v = ps[m][r];
                    v += __shfl_xor(v, 1); v += __shfl_xor(v, 2);
                    v += __shfl_xor(v, 4); v += __shfl_xor(v, 8);
                    ps[m][r] = v;
                }
            if (l15 == 0) {
                #pragma unroll
                for (int m = 0; m < 8; ++m)
                    #pragma unroll
                    for (int r = 0; r < 4; ++r)
                        atomicAdd(&sred[kt * BN + m * 16 + l4 * 4 + r], ps[m][r]);
            }
        }
    }

    if (PASS == 1) {
        #pragma unroll
        for (int n = 0; n < 2; ++n) {
            #pragma unroll
            for (int off = 16; off <= 32; off <<= 1) {
                float ob1 = __shfl_xor(rb1[n], off);
                int   oi  = __shfl_xor(ri1[n], off);
                float ob2 = __shfl_xor(rb2[n], off);
                float ol  = __shfl_xor(rlv[n], off);
                float oT  = __shfl_xor(rTv[n], off);
                online_merge(rb1[n], ri1[n], rb2[n], rlv[n], rTv[n], ob1, oi, ob2, ol, oT);
            }
            if (l4 == 0) {
                int grow = rowBase + wid * 32 + n * 16 + l15;
                P[0 * PF + slice * N_ROWS + grow] = rb1[n];
                P[1 * PF + slice * N_ROWS + grow] = rb2[n];
                P[2 * PF + slice * N_ROWS + grow] = rlv[n];
                P[3 * PF + slice * N_ROWS + grow] = rTv[n];
                ((int*)P)[4 * PF + slice * N_ROWS + grow] = ri1[n];
            }
        }
    } else {
        __syncthreads();
        atomicAdd(&ws[WS_AVGP + slice * SLICE_K + tid], sred[tid]);
        atomicAdd(&ws[WS_AVGP + slice * SLICE_K + tid + 512], sred[tid + 512]);
    }
}

// merge 8 slice-partials per row -> final stats + flags + entropy sum
__global__ void merge_k(const float* __restrict__ P, float* __restrict__ ws) {
    const int tid = threadIdx.x, lane = tid & 63;
    const int row = blockIdx.x * 256 + tid;
    float b1 = 1e30f, b2 = 1e30f, L = 0.f, T = 0.f; int i1 = 0;
    #pragma unroll
    for (int s = 0; s < NSLICE; ++s) {
        float nb1 = P[0 * PF + s * N_ROWS + row];
        float nb2 = P[1 * PF + s * N_ROWS + row];
        float nl  = P[2 * PF + s * N_ROWS + row];
        float nT  = P[3 * PF + s * N_ROWS + row];
        int   ni  = ((const int*)P)[4 * PF + s * N_ROWS + row];
        online_merge(b1, i1, b2, L, T, nb1, ni, nb2, nl, nT);
    }
    ws[WS_BD + row] = b1;
    ((int*)ws)[WS_BI + row] = i1;
    ws[WS_L + row] = L;
    if (b2 - b1 < TAU) {
        int p = atomicAdd(((int*)ws) + WS_FLAGN, 1);
        ((int*)ws)[WS_FLAGL + p] = row;
    }
    float sval = T / L - __logf(L);
    #pragma unroll
    for (int off = 32; off >= 1; off >>= 1) sval += __shfl_xor(sval, off);
    if (lane == 0) atomicAdd(&ws[WS_SCAL + 1], sval);
}

// exact f32 argmin recompute (d2-compare) for flagged rows
__global__ void fixup_k(const float* __restrict__ x, const float* __restrict__ cb,
                        float* __restrict__ ws) {
    __shared__ float xr[DIM];
    __shared__ float rbd[256]; __shared__ int rbi[256];
    const int tid = threadIdx.x;
    const int nf = ((const int*)ws)[WS_FLAGN];
    for (int f = blockIdx.x; f < nf; f += gridDim.x) {
        int row = ((const int*)ws)[WS_FLAGL + f];
        __syncthreads();
        if (tid < 64) ((float4*)xr)[tid] = ((const float4*)(x + (size_t)row * DIM))[tid];
        __syncthreads();
        float x2r = ws[WS_X2 + row];
        float best = 1e30f; int bi = 0;
        for (int c = tid; c < KCODES; c += 256) {
            const float4* crow = (const float4*)(cb + (size_t)c * DIM);
            float dot = 0.f;
            for (int d4 = 0; d4 < 64; ++d4) {
                float4 cv = crow[d4]; float4 xv = ((const float4*)xr)[d4];
                dot = fmaf(cv.x, xv.x, dot); dot = fmaf(cv.y, xv.y, dot);
                dot = fmaf(cv.z, xv.z, dot); dot = fmaf(cv.w, xv.w, dot);
            }
            float d2 = fmaxf(fmaf(-2.f, dot, x2r + ws[WS_C2 + c]), 0.f);
            if (d2 < best) { best = d2; bi = c; }
        }
        rbd[tid] = best; rbi[tid] = bi;
        for (int s = 128; s > 0; s >>= 1) {
            __syncthreads();
            if (tid < s) {
                float ob = rbd[tid + s]; int oi = rbi[tid + s];
                if (ob < rbd[tid] || (ob == rbd[tid] && oi < rbi[tid])) { rbd[tid] = ob; rbi[tid] = oi; }
            }
        }
        __syncthreads();
        if (tid == 0) ((int*)ws)[WS_BI + row] = rbi[0];
    }
}

__global__ void gather_k(const float* __restrict__ x, const float* __restrict__ cb,
                         float* __restrict__ ws, float* __restrict__ outQ,
                         float* __restrict__ outNcbe, float* __restrict__ outIdxF) {
    __shared__ float red2[4];
    const int tid = threadIdx.x, w = tid >> 6, lane = tid & 63;
    float msum = 0.f;
    for (int it = 0; it < 8; ++it) {
        int n = blockIdx.x * 32 + it * 4 + w;
        int idx = ((const int*)ws)[WS_BI + n];
        float4 xv = ((const float4*)(x + (size_t)n * DIM))[lane];
        float4 cv = ((const float4*)(cb + (size_t)idx * DIM))[lane];
        ((float4*)(outQ + (size_t)n * DIM))[lane] = cv;
        float* dst = outNcbe + (size_t)idx * DIM + lane * 4;
        const float g = 0.01f;
        atomicAdd(dst + 0, g * xv.x); atomicAdd(dst + 1, g * xv.y);
        atomicAdd(dst + 2, g * xv.z); atomicAdd(dst + 3, g * xv.w);
        float dx = cv.x - xv.x, dy = cv.y - xv.y, dz = cv.z - xv.z, dw = cv.w - xv.w;
        float s = dx*dx + dy*dy + dz*dz + dw*dw;
        #pragma unroll
        for (int off = 32; off >= 1; off >>= 1) s += __shfl_xor(s, off);
        if (lane == 0) {
            msum += s;
            atomicAdd(&ws[WS_CNT + idx], 1.0f);
            outIdxF[n] = (float)idx;
        }
    }
    if (lane == 0) red2[w] = msum;
    __syncthreads();
    if (tid == 0) atomicAdd(&ws[WS_SCAL + 0], red2[0] + red2[1] + red2[2] + red2[3]);
}

__global__ void stats_k(const float* __restrict__ cse, float* __restrict__ ws,
                        float* __restrict__ outNcse) {
    int tid = threadIdx.x, lane = tid & 63;
    int k = blockIdx.x * 256 + tid;
    float cnt = ws[WS_CNT + k];
    float ncse = 0.99f * cse[k] + 0.01f * cnt;
    outNcse[k] = ncse;
    float ap  = ws[WS_AVGP + k] * (1.0f / N_ROWS);
    float ae  = -(ap * __logf(ap + 1e-5f));
    float app = cnt * (1.0f / N_ROWS);
    float pe  = -(app * __logf(app + 1e-10f));
    #pragma unroll
    for (int off = 32; off >= 1; off >>= 1) {
        ncse += __shfl_xor(ncse, off);
        ae   += __shfl_xor(ae, off);
        pe   += __shfl_xor(pe, off);
    }
    if (lane == 0) {
        atomicAdd(&ws[WS_SCAL + 4], ncse);
        atomicAdd(&ws[WS_SCAL + 2], ae);
        atomicAdd(&ws[WS_SCAL + 3], pe);
    }
}

__global__ void newcb_k(const float* __restrict__ ws, const float* __restrict__ outNcse,
                        const float* __restrict__ outNcbe, float* __restrict__ outNc) {
    int w = threadIdx.x >> 6, lane = threadIdx.x & 63;
    int k = blockIdx.x * 4 + w;
    float n = ws[WS_SCAL + 4];
    float ncse = outNcse[k];
    float smoothed = (ncse + 1e-5f) / (n + (float)KCODES * 1e-5f) * n;
    float inv = 1.0f / smoothed;
    float4 v = ((const float4*)(outNcbe + (size_t)k * DIM))[lane];
    v.x *= inv; v.y *= inv; v.z *= inv; v.w *= inv;
    ((float4*)(outNc + (size_t)k * DIM))[lane] = v;
}

__global__ void finalize_k(const float* __restrict__ ws, float* __restrict__ outLoss,
                           float* __restrict__ outPerp) {
    float mse  = ws[WS_SCAL + 0] * (1.0f / ((float)N_ROWS * 256.0f));
    float sent = -ws[WS_SCAL + 1] * (1.0f / (float)N_ROWS);
    float ent  = sent - ws[WS_SCAL + 2];
    outLoss[0] = 1.25f * mse + 0.1f * ent;
    outPerp[0] = expf(ws[WS_SCAL + 3]);
}

extern "C" void kernel_launch(void* const* d_in, const int* in_sizes, int n_in,
                              void* d_out, int out_size, void* d_ws, size_t ws_size,
                              hipStream_t stream) {
    const float* x   = (const float*)d_in[0];
    const float* cb  = (const float*)d_in[1];
    const float* cse = (const float*)d_in[2];
    const float* cbe = (const float*)d_in[3];
    float* out = (float*)d_out;
    float* ws  = (float*)d_ws;

    float* outQ    = out;
    float* outLoss = out + 8388608;
    float* outPerp = out + 8388609;
    float* outIdxF = out + 8388610;
    float* outNc   = out + 8421378;
    float* outNcse = out + 10518530;
    float* outNcbe = out + 10526722;

    // scratch inside d_out: x splits in outQ, cb splits in outNc(+2 align), partials in outNcbe
    ushort* xh = (ushort*)outQ;
    ushort* xl = xh + (size_t)N_ROWS * DIM;
    ushort* ch = (ushort*)(out + 8421380);
    ushort* cl = ch + (size_t)KCODES * DIM;
    float*  P  = outNcbe;   // 5*PF floats = 5.24 MB

    (void)hipMemsetAsync(ws + WS_AVGP, 0, (size_t)(WS_FLAGN + 1 - WS_AVGP) * sizeof(float), stream);
    split_k<<<N_ROWS * DIM / 2048, 256, 0, stream>>>(x, xh, xl, ws + WS_X2);
    split_k<<<KCODES * DIM / 2048, 256, 0, stream>>>(cb, ch, cl, ws + WS_C2);
    vq_mfma<1><<<NSLICE * (N_ROWS / BM), 512, 0, stream>>>(xh, xl, ch, cl, ws, P);
    merge_k<<<N_ROWS / 256, 256, 0, stream>>>(P, ws);
    vq_mfma<2><<<NSLICE * (N_ROWS / BM), 512, 0, stream>>>(xh, xl, ch, cl, ws, P);
    fixup_k<<<512, 256, 0, stream>>>(x, cb, ws);
    init_ncbe_k<<<2048, 256, 0, stream>>>(cbe, outNcbe);
    gather_k<<<1024, 256, 0, stream>>>(x, cb, ws, outQ, outNcbe, outIdxF);
    stats_k<<<KCODES / 256, 256, 0, stream>>>(cse, ws, outNcse);
    newcb_k<<<KCODES / 4, 256, 0, stream>>>(ws, outNcse, outNcbe, outNc);
    finalize_k<<<1, 1, 0, stream>>>(ws, outLoss, outPerp);
}

// Round 8
// 1458.311 us; speedup vs baseline: 1.3747x; 1.3747x over previous
//
#include <hip/hip_runtime.h>
#include <math.h>

#define N_ROWS 32768
#define DIM 256
#define KCODES 8192

#define BM 128
#define BN 128
#define NSLICE 8
#define SLICE_K 1024
#define CHUNK_R 512
#define NRT (CHUNK_R / BM)        // 4
#define NKT (SLICE_K / BN)        // 8
#define NDT 8
#define NSTEP (NRT * NKT * NDT)   // 256
#define TAU 3e-4f

#define FAST_SQRT(x) __builtin_amdgcn_sqrtf(x)

// ws layout (float offsets)
#define WS_C2    0
#define WS_X2    8192
#define WS_BD    40960
#define WS_BI    73728
#define WS_L     106496
#define WS_FLAGL 139264
#define WS_AVGP  172032
#define WS_CNT   180224
#define WS_SCAL  188416      // 0=mse 1=sum p*logp 2=avg_entropy 3=pent 4=nsum
#define WS_FLAGN 188424

#define PF (NSLICE * N_ROWS)

typedef __bf16 bf16x8 __attribute__((ext_vector_type(8)));
typedef float  f32x4  __attribute__((ext_vector_type(4)));

__device__ __forceinline__ void gll16(const void* g, void* l) {
    __builtin_amdgcn_global_load_lds((const __attribute__((address_space(1))) void*)g,
                                     (__attribute__((address_space(3))) void*)l, 16, 0, 0);
}
__device__ __forceinline__ bf16x8 bcast(uint4 u) { return __builtin_bit_cast(bf16x8, u); }

// split f32 -> hi/lo bf16 + fused row sum-of-squares (8 elems/thread, 8 rows/block)
__global__ void split_k(const float* __restrict__ src, ushort* __restrict__ h,
                        ushort* __restrict__ l, float* __restrict__ norms) {
    int tid = threadIdx.x;
    int i = blockIdx.x * 256 + tid;
    const float4* s4 = (const float4*)src;
    float4 v0 = s4[2 * i], v1 = s4[2 * i + 1];
    float vv[8] = {v0.x, v0.y, v0.z, v0.w, v1.x, v1.y, v1.z, v1.w};
    float nrm = 0.f;
    uint hw[4], lw[4];
    #pragma unroll
    for (int p = 0; p < 4; ++p) {
        float a = vv[2*p], b = vv[2*p+1];
        nrm = fmaf(a, a, nrm); nrm = fmaf(b, b, nrm);
        uint ua = __float_as_uint(a), ub = __float_as_uint(b);
        uint ha = ua & 0xFFFF0000u, hb = ub & 0xFFFF0000u;
        float ra = a - __uint_as_float(ha);
        float rb = b - __uint_as_float(hb);
        hw[p] = hb | (ha >> 16);
        lw[p] = (__float_as_uint(rb) & 0xFFFF0000u) | (__float_as_uint(ra) >> 16);
    }
    ((uint4*)h)[i] = make_uint4(hw[0], hw[1], hw[2], hw[3]);
    ((uint4*)l)[i] = make_uint4(lw[0], lw[1], lw[2], lw[3]);
    #pragma unroll
    for (int off = 16; off >= 1; off >>= 1) nrm += __shfl_xor(nrm, off);
    if ((tid & 31) == 0) norms[blockIdx.x * 8 + (tid >> 5)] = nrm;
}

__global__ void init_ncbe_k(const float* __restrict__ cbe, float* __restrict__ outNcbe) {
    int i = blockIdx.x * 256 + threadIdx.x;
    float4 v = ((const float4*)cbe)[i];
    v.x *= 0.99f; v.y *= 0.99f; v.z *= 0.99f; v.w *= 0.99f;
    ((float4*)outNcbe)[i] = v;
}

__device__ __forceinline__ void online_merge(float& b1, int& i1, float& b2, float& l, float& T,
                                             float nb1, int ni1, float nb2, float nl, float nT) {
    float m  = fminf(b1, nb1);
    float fa = __expf(m - b1);
    float fb = __expf(m - nb1);
    float L  = fa * l + fb * nl;
    float TT = fa * (T + (m - b1) * l) + fb * (nT + (m - nb1) * nl);
    float losing = fmaxf(b1, nb1);
    float B2 = fminf(fminf(b2, nb2), losing);
    if (nb1 < b1 || (nb1 == b1 && ni1 < i1)) i1 = ni1;
    b1 = m; b2 = B2; l = L; T = TT;
}

// PASS 1: per-slice argmin (+2nd) + online softmax partials.  PASS 2: avg_probs for own slice.
// LDS buffer layout (ushorts): cbh[0,4096) cbl[4096,8192) xh[8192,12288) xl[12288,16384)
template<int PASS>
__global__ __launch_bounds__(512, 4) void vq_mfma(const ushort* __restrict__ xh,
                                                  const ushort* __restrict__ xl,
                                                  const ushort* __restrict__ ch,
                                                  const ushort* __restrict__ cl,
                                                  float* __restrict__ ws,
                                                  float* __restrict__ P) {
    __shared__ __align__(16) ushort lds[2][16384];   // 64 KB double buffer
    __shared__ __align__(16) float c2s[SLICE_K];     // 4 KB c2 slice cache
    __shared__ float sred[1536];

    const int tid  = threadIdx.x;
    const int lane = tid & 63, wid = tid >> 6;
    const int wcode = wid & 1, wx = wid >> 1;        // 2 code-groups(64) x 4 row-groups(32)
    const int l15 = lane & 15, l4 = lane >> 4;
    const int slice = blockIdx.x & 7, chunk = blockIdx.x >> 3;
    const int fsw = ((l4 ^ ((l15 >> 1) & 3)) << 3);  // conflict-free read swizzle

    // c2 slice -> LDS (keeps kt-epilogue free of vmem); sred init for PASS2
    c2s[tid]       = ws[WS_C2 + slice * SLICE_K + tid];
    c2s[tid + 512] = ws[WS_C2 + slice * SLICE_K + tid + 512];
    if (PASS == 2) { sred[tid] = 0.f; sred[tid + 512] = 0.f; }

    // staging: thread stages one 16B chunk in each of 4 regions; LDS dst wave-uniform
    const int row_s = tid >> 2;                              // 0..127 tile row
    const int cslot = (tid & 3) ^ ((row_s >> 1) & 3);        // pre-swizzled source octet
    const ushort* bCH = ch + (((size_t)(slice * SLICE_K + row_s)) << 8) + (cslot << 3);
    const ushort* bCL = cl + (((size_t)(slice * SLICE_K + row_s)) << 8) + (cslot << 3);
    const ushort* bXH = xh + (((size_t)(chunk * CHUNK_R + row_s)) << 8) + (cslot << 3);
    const ushort* bXL = xl + (((size_t)(chunk * CHUNK_R + row_s)) << 8) + (cslot << 3);
    const int wdst = wid * 512;                              // uniform per wave (ushorts)

    // prologue: stage t=0 into buf0
    {
        ushort* b0 = &lds[0][0];
        gll16(bCH, b0 + wdst);
        gll16(bCL, b0 + 4096 + wdst);
        gll16(bXH, b0 + 8192 + wdst);
        gll16(bXL, b0 + 12288 + wdst);
    }

    for (int rt = 0; rt < NRT; ++rt) {
        const int rowBase = chunk * CHUNK_R + rt * BM;
        float x2v[2], bdv[2], invl[2];
        #pragma unroll
        for (int n = 0; n < 2; ++n) {
            int rl = wx * 32 + n * 16 + l15;
            x2v[n] = ws[WS_X2 + rowBase + rl];
            if (PASS == 2) {
                bdv[n]  = ws[WS_BD + rowBase + rl];
                invl[n] = 1.0f / ws[WS_L + rowBase + rl];
            }
        }
        float rb1[2], rb2[2], rlv[2], rTv[2]; int ri1[2];
        #pragma unroll
        for (int n = 0; n < 2; ++n) { rb1[n] = 1e30f; rb2[n] = 1e30f; rlv[n] = 0.f; rTv[n] = 0.f; ri1[n] = 0; }

        for (int kt = 0; kt < NKT; ++kt) {
            f32x4 acc[4][2];
            #pragma unroll
            for (int m = 0; m < 4; ++m) {
                acc[m][0] = (f32x4){0.f, 0.f, 0.f, 0.f};
                acc[m][1] = (f32x4){0.f, 0.f, 0.f, 0.f};
            }

            #pragma unroll
            for (int dt = 0; dt < NDT; ++dt) {
                const int t = rt * 64 + kt * 8 + dt;
                if (t + 1 < NSTEP) {
                    const int t1 = t + 1;
                    const int cbo = (((t1 >> 3) & 7) << 15) | ((t1 & 7) << 5);
                    const int xo  = ((t1 >> 6) << 15) | ((t1 & 7) << 5);
                    ushort* wb = &lds[t1 & 1][0];
                    gll16(bCH + cbo, wb + wdst);
                    gll16(bCL + cbo, wb + 4096 + wdst);
                    gll16(bXH + xo,  wb + 8192 + wdst);
                    gll16(bXL + xo,  wb + 12288 + wdst);
                    asm volatile("s_waitcnt vmcnt(4)" ::: "memory");   // stage(t) landed; t+1 in flight
                } else {
                    asm volatile("s_waitcnt vmcnt(0)" ::: "memory");
                }
                __builtin_amdgcn_s_barrier();            // all waves' stage(t) visible
                __builtin_amdgcn_sched_barrier(0);

                const ushort* bb = &lds[t & 1][0];
                bf16x8 bhf[2], blf[2];
                #pragma unroll
                for (int n = 0; n < 2; ++n) {
                    int off = (wx * 32 + n * 16 + l15) * 32 + fsw;
                    bhf[n] = bcast(*(const uint4*)(bb + 8192 + off));
                    blf[n] = bcast(*(const uint4*)(bb + 12288 + off));
                }
                __builtin_amdgcn_s_setprio(1);
                #pragma unroll
                for (int m = 0; m < 4; ++m) {
                    int off = (wcode * 64 + m * 16 + l15) * 32 + fsw;
                    bf16x8 ah = bcast(*(const uint4*)(bb + off));
                    bf16x8 al = bcast(*(const uint4*)(bb + 4096 + off));
                    acc[m][0] = __builtin_amdgcn_mfma_f32_16x16x32_bf16(ah, bhf[0], acc[m][0], 0, 0, 0);
                    acc[m][0] = __builtin_amdgcn_mfma_f32_16x16x32_bf16(ah, blf[0], acc[m][0], 0, 0, 0);
                    acc[m][0] = __builtin_amdgcn_mfma_f32_16x16x32_bf16(al, bhf[0], acc[m][0], 0, 0, 0);
                    acc[m][1] = __builtin_amdgcn_mfma_f32_16x16x32_bf16(ah, bhf[1], acc[m][1], 0, 0, 0);
                    acc[m][1] = __builtin_amdgcn_mfma_f32_16x16x32_bf16(ah, blf[1], acc[m][1], 0, 0, 0);
                    acc[m][1] = __builtin_amdgcn_mfma_f32_16x16x32_bf16(al, bhf[1], acc[m][1], 0, 0, 0);
                }
                __builtin_amdgcn_s_setprio(0);
                __builtin_amdgcn_sched_barrier(0);
                __builtin_amdgcn_s_barrier();            // all reads of buf[t&1] done before t+2 writes land
            }

            // epilogue: lane holds D[code=(l4*4+r)+16m][xrow=l15+16n]; no vmem here
            const int cb0 = slice * SLICE_K + kt * BN + wcode * 64 + l4 * 4;
            const int lc0 = kt * BN + wcode * 64 + l4 * 4;
            if (PASS == 1) {
                #pragma unroll
                for (int n = 0; n < 2; ++n) {
                    #pragma unroll
                    for (int m = 0; m < 4; ++m) {
                        float4 c2v = *(const float4*)&c2s[lc0 + m * 16];
                        float dsv[4];
                        float b1 = 1e30f, b2 = 1e30f; int i1 = 0;
                        #pragma unroll
                        for (int r = 0; r < 4; ++r) {
                            float d2 = fmaf(-2.f, acc[m][n][r], x2v[n] + ((const float*)&c2v)[r]);
                            float dv = FAST_SQRT(fmaxf(d2, 0.f));
                            dsv[r] = dv;
                            bool better = dv < b1;
                            b2 = better ? b1 : fminf(b2, dv);
                            if (better) { b1 = dv; i1 = cb0 + m * 16 + r; }
                        }
                        float ls = 0.f, ts = 0.f;
                        #pragma unroll
                        for (int r = 0; r < 4; ++r) {
                            float e = __expf(b1 - dsv[r]);
                            ls += e;
                            ts = fmaf(e, b1 - dsv[r], ts);
                        }
                        online_merge(rb1[n], ri1[n], rb2[n], rlv[n], rTv[n], b1, i1, b2, ls, ts);
                    }
                }
            } else {
                float ps[4][4];
                #pragma unroll
                for (int m = 0; m < 4; ++m)
                    #pragma unroll
                    for (int r = 0; r < 4; ++r) ps[m][r] = 0.f;
                #pragma unroll
                for (int n = 0; n < 2; ++n) {
                    #pragma unroll
                    for (int m = 0; m < 4; ++m) {
                        float4 c2v = *(const float4*)&c2s[lc0 + m * 16];
                        #pragma unroll
                        for (int r = 0; r < 4; ++r) {
                            float d2 = fmaf(-2.f, acc[m][n][r], x2v[n] + ((const float*)&c2v)[r]);
                            float dv = FAST_SQRT(fmaxf(d2, 0.f));
                            ps[m][r] = fmaf(__expf(bdv[n] - dv), invl[n], ps[m][r]);
                        }
                    }
                }
                #pragma unroll
                for (int m = 0; m < 4; ++m)
                    #pragma unroll
                    for (int r = 0; r < 4; ++r) {
                        float v = ps[m][r];
                        v += __shfl_xor(v, 1); v += __shfl_xor(v, 2);
                        v += __shfl_xor(v, 4); v += __shfl_xor(v, 8);
                        ps[m][r] = v;
                    }
                if (l15 == 0) {
                    #pragma unroll
                    for (int m = 0; m < 4; ++m)
                        #pragma unroll
                        for (int r = 0; r < 4; ++r)
                            atomicAdd(&sred[lc0 + m * 16 + r], ps[m][r]);
                }
            }
        }

        if (PASS == 1) {
            #pragma unroll
            for (int n = 0; n < 2; ++n) {
                #pragma unroll
                for (int off = 16; off <= 32; off <<= 1) {
                    float ob1 = __shfl_xor(rb1[n], off);
                    int   oi  = __shfl_xor(ri1[n], off);
                    float ob2 = __shfl_xor(rb2[n], off);
                    float ol  = __shfl_xor(rlv[n], off);
                    float oT  = __shfl_xor(rTv[n], off);
                    online_merge(rb1[n], ri1[n], rb2[n], rlv[n], rTv[n], ob1, oi, ob2, ol, oT);
                }
            }
            if (l4 == 0) {
                #pragma unroll
                for (int n = 0; n < 2; ++n) {
                    int rl = wx * 32 + n * 16 + l15;
                    sred[(rl << 1) + wcode]       = rb1[n];
                    sred[256 + (rl << 1) + wcode] = rb2[n];
                    sred[512 + (rl << 1) + wcode] = rlv[n];
                    sred[768 + (rl << 1) + wcode] = rTv[n];
                    ((int*)sred)[1024 + (rl << 1) + wcode] = ri1[n];
                }
            }
            __syncthreads();
            if (tid < BM) {
                float b1 = sred[tid * 2];       int i1 = ((int*)sred)[1024 + tid * 2];
                float b2 = sred[256 + tid * 2];
                float L  = sred[512 + tid * 2];
                float T  = sred[768 + tid * 2];
                online_merge(b1, i1, b2, L, T,
                             sred[tid * 2 + 1], ((int*)sred)[1024 + tid * 2 + 1],
                             sred[256 + tid * 2 + 1], sred[512 + tid * 2 + 1], sred[768 + tid * 2 + 1]);
                int grow = rowBase + tid;
                P[0 * PF + slice * N_ROWS + grow] = b1;
                P[1 * PF + slice * N_ROWS + grow] = b2;
                P[2 * PF + slice * N_ROWS + grow] = L;
                P[3 * PF + slice * N_ROWS + grow] = T;
                ((int*)P)[4 * PF + slice * N_ROWS + grow] = i1;
            }
            __syncthreads();
        }
    }

    if (PASS == 2) {
        __syncthreads();
        atomicAdd(&ws[WS_AVGP + slice * SLICE_K + tid], sred[tid]);
        atomicAdd(&ws[WS_AVGP + slice * SLICE_K + tid + 512], sred[tid + 512]);
    }
}

// merge 8 slice-partials per row -> final stats + flags + entropy sum
__global__ void merge_k(const float* __restrict__ P, float* __restrict__ ws) {
    const int tid = threadIdx.x, lane = tid & 63;
    const int row = blockIdx.x * 256 + tid;
    float b1 = 1e30f, b2 = 1e30f, L = 0.f, T = 0.f; int i1 = 0;
    #pragma unroll
    for (int s = 0; s < NSLICE; ++s) {
        float nb1 = P[0 * PF + s * N_ROWS + row];
        float nb2 = P[1 * PF + s * N_ROWS + row];
        float nl  = P[2 * PF + s * N_ROWS + row];
        float nT  = P[3 * PF + s * N_ROWS + row];
        int   ni  = ((const int*)P)[4 * PF + s * N_ROWS + row];
        online_merge(b1, i1, b2, L, T, nb1, ni, nb2, nl, nT);
    }
    ws[WS_BD + row] = b1;
    ((int*)ws)[WS_BI + row] = i1;
    ws[WS_L + row] = L;
    if (b2 - b1 < TAU) {
        int p = atomicAdd(((int*)ws) + WS_FLAGN, 1);
        ((int*)ws)[WS_FLAGL + p] = row;
    }
    float sval = T / L - __logf(L);
    #pragma unroll
    for (int off = 32; off >= 1; off >>= 1) sval += __shfl_xor(sval, off);
    if (lane == 0) atomicAdd(&ws[WS_SCAL + 1], sval);
}

// exact f32 argmin recompute (d2-compare) for flagged rows
__global__ void fixup_k(const float* __restrict__ x, const float* __restrict__ cb,
                        float* __restrict__ ws) {
    __shared__ float xr[DIM];
    __shared__ float rbd[256]; __shared__ int rbi[256];
    const int tid = threadIdx.x;
    const int nf = ((const int*)ws)[WS_FLAGN];
    for (int f = blockIdx.x; f < nf; f += gridDim.x) {
        int row = ((const int*)ws)[WS_FLAGL + f];
        __syncthreads();
        if (tid < 64) ((float4*)xr)[tid] = ((const float4*)(x + (size_t)row * DIM))[tid];
        __syncthreads();
        float x2r = ws[WS_X2 + row];
        float best = 1e30f; int bi = 0;
        for (int c = tid; c < KCODES; c += 256) {
            const float4* crow = (const float4*)(cb + (size_t)c * DIM);
            float dot = 0.f;
            for (int d4 = 0; d4 < 64; ++d4) {
                float4 cv = crow[d4]; float4 xv = ((const float4*)xr)[d4];
                dot = fmaf(cv.x, xv.x, dot); dot = fmaf(cv.y, xv.y, dot);
                dot = fmaf(cv.z, xv.z, dot); dot = fmaf(cv.w, xv.w, dot);
            }
            float d2 = fmaxf(fmaf(-2.f, dot, x2r + ws[WS_C2 + c]), 0.f);
            if (d2 < best) { best = d2; bi = c; }
        }
        rbd[tid] = best; rbi[tid] = bi;
        for (int s = 128; s > 0; s >>= 1) {
            __syncthreads();
            if (tid < s) {
                float ob = rbd[tid + s]; int oi = rbi[tid + s];
                if (ob < rbd[tid] || (ob == rbd[tid] && oi < rbi[tid])) { rbd[tid] = ob; rbi[tid] = oi; }
            }
        }
        __syncthreads();
        if (tid == 0) ((int*)ws)[WS_BI + row] = rbi[0];
    }
}

__global__ void gather_k(const float* __restrict__ x, const float* __restrict__ cb,
                         float* __restrict__ ws, float* __restrict__ outQ,
                         float* __restrict__ outNcbe, float* __restrict__ outIdxF) {
    __shared__ float red2[4];
    const int tid = threadIdx.x, w = tid >> 6, lane = tid & 63;
    float msum = 0.f;
    for (int it = 0; it < 8; ++it) {
        int n = blockIdx.x * 32 + it * 4 + w;
        int idx = ((const int*)ws)[WS_BI + n];
        float4 xv = ((const float4*)(x + (size_t)n * DIM))[lane];
        float4 cv = ((const float4*)(cb + (size_t)idx * DIM))[lane];
        ((float4*)(outQ + (size_t)n * DIM))[lane] = cv;
        float* dst = outNcbe + (size_t)idx * DIM + lane * 4;
        const float g = 0.01f;
        atomicAdd(dst + 0, g * xv.x); atomicAdd(dst + 1, g * xv.y);
        atomicAdd(dst + 2, g * xv.z); atomicAdd(dst + 3, g * xv.w);
        float dx = cv.x - xv.x, dy = cv.y - xv.y, dz = cv.z - xv.z, dw = cv.w - xv.w;
        float s = dx*dx + dy*dy + dz*dz + dw*dw;
        #pragma unroll
        for (int off = 32; off >= 1; off >>= 1) s += __shfl_xor(s, off);
        if (lane == 0) {
            msum += s;
            atomicAdd(&ws[WS_CNT + idx], 1.0f);
            outIdxF[n] = (float)idx;
        }
    }
    if (lane == 0) red2[w] = msum;
    __syncthreads();
    if (tid == 0) atomicAdd(&ws[WS_SCAL + 0], red2[0] + red2[1] + red2[2] + red2[3]);
}

__global__ void stats_k(const float* __restrict__ cse, float* __restrict__ ws,
                        float* __restrict__ outNcse) {
    int tid = threadIdx.x, lane = tid & 63;
    int k = blockIdx.x * 256 + tid;
    float cnt = ws[WS_CNT + k];
    float ncse = 0.99f * cse[k] + 0.01f * cnt;
    outNcse[k] = ncse;
    float ap  = ws[WS_AVGP + k] * (1.0f / N_ROWS);
    float ae  = -(ap * __logf(ap + 1e-5f));
    float app = cnt * (1.0f / N_ROWS);
    float pe  = -(app * __logf(app + 1e-10f));
    #pragma unroll
    for (int off = 32; off >= 1; off >>= 1) {
        ncse += __shfl_xor(ncse, off);
        ae   += __shfl_xor(ae, off);
        pe   += __shfl_xor(pe, off);
    }
    if (lane == 0) {
        atomicAdd(&ws[WS_SCAL + 4], ncse);
        atomicAdd(&ws[WS_SCAL + 2], ae);
        atomicAdd(&ws[WS_SCAL + 3], pe);
    }
}

__global__ void newcb_k(const float* __restrict__ ws, const float* __restrict__ outNcse,
                        const float* __restrict__ outNcbe, float* __restrict__ outNc) {
    int w = threadIdx.x >> 6, lane = threadIdx.x & 63;
    int k = blockIdx.x * 4 + w;
    float n = ws[WS_SCAL + 4];
    float ncse = outNcse[k];
    float smoothed = (ncse + 1e-5f) / (n + (float)KCODES * 1e-5f) * n;
    float inv = 1.0f / smoothed;
    float4 v = ((const float4*)(outNcbe + (size_t)k * DIM))[lane];
    v.x *= inv; v.y *= inv; v.z *= inv; v.w *= inv;
    ((float4*)(outNc + (size_t)k * DIM))[lane] = v;
}

__global__ void finalize_k(const float* __restrict__ ws, float* __restrict__ outLoss,
                           float* __restrict__ outPerp) {
    float mse  = ws[WS_SCAL + 0] * (1.0f / ((float)N_ROWS * 256.0f));
    float sent = -ws[WS_SCAL + 1] * (1.0f / (float)N_ROWS);
    float ent  = sent - ws[WS_SCAL + 2];
    outLoss[0] = 1.25f * mse + 0.1f * ent;
    outPerp[0] = expf(ws[WS_SCAL + 3]);
}

extern "C" void kernel_launch(void* const* d_in, const int* in_sizes, int n_in,
                              void* d_out, int out_size, void* d_ws, size_t ws_size,
                              hipStream_t stream) {
    const float* x   = (const float*)d_in[0];
    const float* cb  = (const float*)d_in[1];
    const float* cse = (const float*)d_in[2];
    const float* cbe = (const float*)d_in[3];
    float* out = (float*)d_out;
    float* ws  = (float*)d_ws;

    float* outQ    = out;
    float* outLoss = out + 8388608;
    float* outPerp = out + 8388609;
    float* outIdxF = out + 8388610;
    float* outNc   = out + 8421378;
    float* outNcse = out + 10518530;
    float* outNcbe = out + 10526722;

    // scratch inside d_out: x splits in outQ, cb splits in outNc(+2 align), partials in outNcbe
    ushort* xh = (ushort*)outQ;
    ushort* xl = xh + (size_t)N_ROWS * DIM;
    ushort* ch = (ushort*)(out + 8421380);
    ushort* cl = ch + (size_t)KCODES * DIM;
    float*  P  = outNcbe;   // 5*PF floats = 5.24 MB

    (void)hipMemsetAsync(ws + WS_AVGP, 0, (size_t)(WS_FLAGN + 1 - WS_AVGP) * sizeof(float), stream);
    split_k<<<N_ROWS * DIM / 2048, 256, 0, stream>>>(x, xh, xl, ws + WS_X2);
    split_k<<<KCODES * DIM / 2048, 256, 0, stream>>>(cb, ch, cl, ws + WS_C2);
    vq_mfma<1><<<NSLICE * (N_ROWS / CHUNK_R), 512, 0, stream>>>(xh, xl, ch, cl, ws, P);
    merge_k<<<N_ROWS / 256, 256, 0, stream>>>(P, ws);
    vq_mfma<2><<<NSLICE * (N_ROWS / CHUNK_R), 512, 0, stream>>>(xh, xl, ch, cl, ws, P);
    fixup_k<<<512, 256, 0, stream>>>(x, cb, ws);
    init_ncbe_k<<<2048, 256, 0, stream>>>(cbe, outNcbe);
    gather_k<<<1024, 256, 0, stream>>>(x, cb, ws, outQ, outNcbe, outIdxF);
    stats_k<<<KCODES / 256, 256, 0, stream>>>(cse, ws, outNcse);
    newcb_k<<<KCODES / 4, 256, 0, stream>>>(ws, outNcse, outNcbe, outNc);
    finalize_k<<<1, 1, 0, stream>>>(ws, outLoss, outPerp);
}